// Round 1
// baseline (278.739 us; speedup 1.0000x reference)
//
#include <hip/hip_runtime.h>

// LQActiv forward: 2-bit quantization + least-squares basis refit.
// Output layout: [N floats wq][2 floats new_basis].
//
// Kernel 1 (lq_main): grid-stride float4 pass. Computes wq, accumulates
//   S01 = sum(b0*b1), Sb0 = sum(b0*w), Sb1 = sum(b1*w) per block and writes
//   deterministic per-block partials to d_ws (no atomics -> deterministic).
// Kernel 2 (lq_final): reduces 2048*3 partials in f64, solves the 2x2
//   system, writes new_basis.

#define NBLOCKS 2048
#define NTHREADS 256

__global__ __launch_bounds__(NTHREADS) void lq_main(
    const float* __restrict__ x, const float* __restrict__ basis,
    float* __restrict__ out, float* __restrict__ partials,
    int n, int n4) {
  // --- build sorted quantization levels + encodings from basis (loop-invariant) ---
  const float v0 = basis[0], v1 = basis[1];
  float lev[4] = {-v0 - v1, -v0 + v1, v0 - v1, v0 + v1};
  float e0[4] = {-1.f, -1.f, 1.f, 1.f};
  float e1[4] = {-1.f, 1.f, -1.f, 1.f};
  // 4-element sorting network (all indices compile-time constants)
#define CSWAP(i, j)                                                   \
  if (lev[i] > lev[j]) {                                              \
    float t = lev[i]; lev[i] = lev[j]; lev[j] = t;                    \
    t = e0[i]; e0[i] = e0[j]; e0[j] = t;                              \
    t = e1[i]; e1[i] = e1[j]; e1[j] = t;                              \
  }
  CSWAP(0, 1) CSWAP(2, 3) CSWAP(0, 2) CSWAP(1, 3) CSWAP(1, 2)
#undef CSWAP
  const float Q0 = lev[0], Q1 = lev[1], Q2 = lev[2], Q3 = lev[3];
  const float A0 = e0[0], A1 = e0[1], A2 = e0[2], A3 = e0[3];
  const float B0 = e1[0], B1 = e1[1], B2 = e1[2], B3 = e1[3];
  const float T0 = 0.5f * (Q0 + Q1);
  const float T1 = 0.5f * (Q1 + Q2);
  const float T2 = 0.5f * (Q2 + Q3);

  float s01 = 0.f, sb0 = 0.f, sb1 = 0.f;

  const int tid = blockIdx.x * blockDim.x + threadIdx.x;
  const int stride = gridDim.x * blockDim.x;

  // branchless bucket select: idx = (w>T0)+(w>T1)+(w>T2)  (searchsorted left)
  auto proc = [&](float w) -> float {
    float q = Q0, b0 = A0, b1 = B0;
    if (w > T0) { q = Q1; b0 = A1; b1 = B1; }
    if (w > T1) { q = Q2; b0 = A2; b1 = B2; }
    if (w > T2) { q = Q3; b0 = A3; b1 = B3; }
    s01 += b0 * b1;
    sb0 = fmaf(b0, w, sb0);
    sb1 = fmaf(b1, w, sb1);
    return q;
  };

  const float4* __restrict__ x4 = (const float4*)x;
  float4* __restrict__ o4 = (float4*)out;
  for (int i = tid; i < n4; i += stride) {
    float4 w = x4[i];
    float4 q;
    q.x = proc(w.x);
    q.y = proc(w.y);
    q.z = proc(w.z);
    q.w = proc(w.w);
    o4[i] = q;
  }
  // scalar tail (n % 4 != 0 safety; N here is divisible by 4)
  for (int i = n4 * 4 + tid; i < n; i += stride) {
    out[i] = proc(x[i]);
  }

  // --- block reduction: wave shfl, then LDS across the 4 waves ---
  for (int off = 32; off; off >>= 1) {
    s01 += __shfl_down(s01, off);
    sb0 += __shfl_down(sb0, off);
    sb1 += __shfl_down(sb1, off);
  }
  __shared__ float red[3][NTHREADS / 64];
  const int lane = threadIdx.x & 63;
  const int wid = threadIdx.x >> 6;
  if (lane == 0) {
    red[0][wid] = s01;
    red[1][wid] = sb0;
    red[2][wid] = sb1;
  }
  __syncthreads();
  if (threadIdx.x == 0) {
    float r01 = 0.f, rb0 = 0.f, rb1 = 0.f;
#pragma unroll
    for (int w = 0; w < NTHREADS / 64; ++w) {
      r01 += red[0][w];
      rb0 += red[1][w];
      rb1 += red[2][w];
    }
    partials[3 * blockIdx.x + 0] = r01;
    partials[3 * blockIdx.x + 1] = rb0;
    partials[3 * blockIdx.x + 2] = rb1;
  }
}

__global__ __launch_bounds__(NTHREADS) void lq_final(
    const float* __restrict__ partials, const float* __restrict__ basis,
    float* __restrict__ out_basis, int n, int nparts) {
  double s01 = 0.0, sb0 = 0.0, sb1 = 0.0;
  for (int i = threadIdx.x; i < nparts; i += blockDim.x) {
    s01 += (double)partials[3 * i + 0];
    sb0 += (double)partials[3 * i + 1];
    sb1 += (double)partials[3 * i + 2];
  }
  for (int off = 32; off; off >>= 1) {
    s01 += __shfl_down(s01, off);
    sb0 += __shfl_down(sb0, off);
    sb1 += __shfl_down(sb1, off);
  }
  __shared__ double red[3][NTHREADS / 64];
  const int lane = threadIdx.x & 63;
  const int wid = threadIdx.x >> 6;
  if (lane == 0) {
    red[0][wid] = s01;
    red[1][wid] = sb0;
    red[2][wid] = sb1;
  }
  __syncthreads();
  if (threadIdx.x == 0) {
    double S01 = 0.0, Sb0 = 0.0, Sb1 = 0.0;
#pragma unroll
    for (int w = 0; w < NTHREADS / 64; ++w) {
      S01 += red[0][w];
      Sb0 += red[1][w];
      Sb1 += red[2][w];
    }
    const double N = (double)n;
    // A = [[N, S01],[S01, N]]; v = A^{-1} b
    const double det = N * N - S01 * S01;
    const double nv0 = (N * Sb0 - S01 * Sb1) / det;
    const double nv1 = (N * Sb1 - S01 * Sb0) / det;
    out_basis[0] = (float)(0.9 * (double)basis[0] + 0.1 * nv0);
    out_basis[1] = (float)(0.9 * (double)basis[1] + 0.1 * nv1);
  }
}

extern "C" void kernel_launch(void* const* d_in, const int* in_sizes, int n_in,
                              void* d_out, int out_size, void* d_ws, size_t ws_size,
                              hipStream_t stream) {
  const float* x = (const float*)d_in[0];
  const float* basis = (const float*)d_in[1];
  float* out = (float*)d_out;
  const int n = in_sizes[0];
  float* partials = (float*)d_ws;  // NBLOCKS * 3 floats

  const int n4 = n / 4;
  lq_main<<<NBLOCKS, NTHREADS, 0, stream>>>(x, basis, out, partials, n, n4);
  lq_final<<<1, NTHREADS, 0, stream>>>(partials, basis, out + n, n, NBLOCKS);
}

// Round 3
// 249.258 us; speedup vs baseline: 1.1183x; 1.1183x over previous
//
#include <hip/hip_runtime.h>

// LQActiv forward: 2-bit quantization + least-squares basis refit.
// Output layout: [N floats wq][2 floats new_basis].
//
// Round 3: nontemporal loads/stores via native clang ext_vector_type
// (HIP float4 is a struct and is rejected by the builtin) + 2-deep unroll.
//
// Kernel 1 (lq_main): grid-stride 16B-vector pass. Computes wq, accumulates
//   S01 = sum(b0*b1), Sb0 = sum(b0*w), Sb1 = sum(b1*w) per block and writes
//   deterministic per-block partials to d_ws (no atomics -> deterministic).
// Kernel 2 (lq_final): reduces 2048*3 partials in f64, solves the 2x2
//   system, writes new_basis.

#define NBLOCKS 2048
#define NTHREADS 256

typedef float fvec4 __attribute__((ext_vector_type(4)));

__global__ __launch_bounds__(NTHREADS) void lq_main(
    const float* __restrict__ x, const float* __restrict__ basis,
    float* __restrict__ out, float* __restrict__ partials,
    int n, int n4) {
  // --- build sorted quantization levels + encodings from basis (loop-invariant) ---
  const float v0 = basis[0], v1 = basis[1];
  float lev[4] = {-v0 - v1, -v0 + v1, v0 - v1, v0 + v1};
  float e0[4] = {-1.f, -1.f, 1.f, 1.f};
  float e1[4] = {-1.f, 1.f, -1.f, 1.f};
  // 4-element sorting network (all indices compile-time constants)
#define CSWAP(i, j)                                                   \
  if (lev[i] > lev[j]) {                                              \
    float t = lev[i]; lev[i] = lev[j]; lev[j] = t;                    \
    t = e0[i]; e0[i] = e0[j]; e0[j] = t;                              \
    t = e1[i]; e1[i] = e1[j]; e1[j] = t;                              \
  }
  CSWAP(0, 1) CSWAP(2, 3) CSWAP(0, 2) CSWAP(1, 3) CSWAP(1, 2)
#undef CSWAP
  const float Q0 = lev[0], Q1 = lev[1], Q2 = lev[2], Q3 = lev[3];
  const float A0 = e0[0], A1 = e0[1], A2 = e0[2], A3 = e0[3];
  const float B0 = e1[0], B1 = e1[1], B2 = e1[2], B3 = e1[3];
  const float T0 = 0.5f * (Q0 + Q1);
  const float T1 = 0.5f * (Q1 + Q2);
  const float T2 = 0.5f * (Q2 + Q3);

  float s01 = 0.f, sb0 = 0.f, sb1 = 0.f;

  const int tid = blockIdx.x * blockDim.x + threadIdx.x;
  const int stride = gridDim.x * blockDim.x;

  // branchless bucket select: idx = (w>T0)+(w>T1)+(w>T2)  (searchsorted left)
  auto proc = [&](float w) -> float {
    float q = Q0, b0 = A0, b1 = B0;
    if (w > T0) { q = Q1; b0 = A1; b1 = B1; }
    if (w > T1) { q = Q2; b0 = A2; b1 = B2; }
    if (w > T2) { q = Q3; b0 = A3; b1 = B3; }
    s01 += b0 * b1;
    sb0 = fmaf(b0, w, sb0);
    sb1 = fmaf(b1, w, sb1);
    return q;
  };

  const fvec4* __restrict__ x4 = (const fvec4*)x;
  fvec4* __restrict__ o4 = (fvec4*)out;

  int i = tid;
  // 2-deep: two independent nontemporal dwordx4 loads in flight
  for (; i + stride < n4; i += 2 * stride) {
    fvec4 wa = __builtin_nontemporal_load(&x4[i]);
    fvec4 wb = __builtin_nontemporal_load(&x4[i + stride]);
    fvec4 qa, qb;
    qa.x = proc(wa.x);
    qa.y = proc(wa.y);
    qa.z = proc(wa.z);
    qa.w = proc(wa.w);
    qb.x = proc(wb.x);
    qb.y = proc(wb.y);
    qb.z = proc(wb.z);
    qb.w = proc(wb.w);
    __builtin_nontemporal_store(qa, &o4[i]);
    __builtin_nontemporal_store(qb, &o4[i + stride]);
  }
  for (; i < n4; i += stride) {
    fvec4 w = __builtin_nontemporal_load(&x4[i]);
    fvec4 q;
    q.x = proc(w.x);
    q.y = proc(w.y);
    q.z = proc(w.z);
    q.w = proc(w.w);
    __builtin_nontemporal_store(q, &o4[i]);
  }
  // scalar tail (n % 4 != 0 safety; N here is divisible by 4)
  for (int k = n4 * 4 + tid; k < n; k += stride) {
    out[k] = proc(x[k]);
  }

  // --- block reduction: wave shfl, then LDS across the 4 waves ---
  for (int off = 32; off; off >>= 1) {
    s01 += __shfl_down(s01, off);
    sb0 += __shfl_down(sb0, off);
    sb1 += __shfl_down(sb1, off);
  }
  __shared__ float red[3][NTHREADS / 64];
  const int lane = threadIdx.x & 63;
  const int wid = threadIdx.x >> 6;
  if (lane == 0) {
    red[0][wid] = s01;
    red[1][wid] = sb0;
    red[2][wid] = sb1;
  }
  __syncthreads();
  if (threadIdx.x == 0) {
    float r01 = 0.f, rb0 = 0.f, rb1 = 0.f;
#pragma unroll
    for (int w = 0; w < NTHREADS / 64; ++w) {
      r01 += red[0][w];
      rb0 += red[1][w];
      rb1 += red[2][w];
    }
    partials[3 * blockIdx.x + 0] = r01;
    partials[3 * blockIdx.x + 1] = rb0;
    partials[3 * blockIdx.x + 2] = rb1;
  }
}

__global__ __launch_bounds__(NTHREADS) void lq_final(
    const float* __restrict__ partials, const float* __restrict__ basis,
    float* __restrict__ out_basis, int n, int nparts) {
  double s01 = 0.0, sb0 = 0.0, sb1 = 0.0;
  for (int i = threadIdx.x; i < nparts; i += blockDim.x) {
    s01 += (double)partials[3 * i + 0];
    sb0 += (double)partials[3 * i + 1];
    sb1 += (double)partials[3 * i + 2];
  }
  for (int off = 32; off; off >>= 1) {
    s01 += __shfl_down(s01, off);
    sb0 += __shfl_down(sb0, off);
    sb1 += __shfl_down(sb1, off);
  }
  __shared__ double red[3][NTHREADS / 64];
  const int lane = threadIdx.x & 63;
  const int wid = threadIdx.x >> 6;
  if (lane == 0) {
    red[0][wid] = s01;
    red[1][wid] = sb0;
    red[2][wid] = sb1;
  }
  __syncthreads();
  if (threadIdx.x == 0) {
    double S01 = 0.0, Sb0 = 0.0, Sb1 = 0.0;
#pragma unroll
    for (int w = 0; w < NTHREADS / 64; ++w) {
      S01 += red[0][w];
      Sb0 += red[1][w];
      Sb1 += red[2][w];
    }
    const double N = (double)n;
    // A = [[N, S01],[S01, N]]; v = A^{-1} b
    const double det = N * N - S01 * S01;
    const double nv0 = (N * Sb0 - S01 * Sb1) / det;
    const double nv1 = (N * Sb1 - S01 * Sb0) / det;
    out_basis[0] = (float)(0.9 * (double)basis[0] + 0.1 * nv0);
    out_basis[1] = (float)(0.9 * (double)basis[1] + 0.1 * nv1);
  }
}

extern "C" void kernel_launch(void* const* d_in, const int* in_sizes, int n_in,
                              void* d_out, int out_size, void* d_ws, size_t ws_size,
                              hipStream_t stream) {
  const float* x = (const float*)d_in[0];
  const float* basis = (const float*)d_in[1];
  float* out = (float*)d_out;
  const int n = in_sizes[0];
  float* partials = (float*)d_ws;  // NBLOCKS * 3 floats

  const int n4 = n / 4;
  lq_main<<<NBLOCKS, NTHREADS, 0, stream>>>(x, basis, out, partials, n, n4);
  lq_final<<<1, NTHREADS, 0, stream>>>(partials, basis, out + n, n, NBLOCKS);
}